// Round 5
// baseline (9334.724 us; speedup 1.0000x reference)
//
#include <hip/hip_runtime.h>
#include <hip/hip_fp16.h>
#include <math.h>

#define B_    32
#define TE    1024
#define TD    512
#define E_    512
#define F_    32
#define K_    31
#define KH    15
#define CHUNK 64
#define NCH   (TE / CHUNK)        // 16 chunks per batch row
#define NBLK  256                 // one block per (bA, chunk); handles bA and bA+16

typedef __attribute__((ext_vector_type(8))) short short8;
typedef __attribute__((ext_vector_type(4))) float f32x4;

#define KKc   2.885390081777927f  // 2*log2(e)

__device__ __forceinline__ unsigned short f2bf(float x) {   // RNE f32->bf16
    unsigned u = __float_as_uint(x);
    unsigned r = (u + 0x7fffu + ((u >> 16) & 1u)) >> 16;
    return (unsigned short)r;
}
__device__ __forceinline__ float bf2f(unsigned short h) {
    return __uint_as_float(((unsigned)h) << 16);
}

// Agent-scope accessors: cross-XCD coherent without cache-wide invalidates.
__device__ __forceinline__ float gldf(const float* p) {
    return __hip_atomic_load(p, __ATOMIC_RELAXED, __HIP_MEMORY_SCOPE_AGENT);
}
__device__ __forceinline__ void gstf(float* p, float v) {
    __hip_atomic_store(p, v, __ATOMIC_RELAXED, __HIP_MEMORY_SCOPE_AGENT);
}

// ---------------------------------------------------------------------------
// Prologue: w_loc (F,U) -> transposed bf16 [u][c], PRE-SCALED by KK=2*log2(e).
// Zero-inits the 512 step flags.
// ---------------------------------------------------------------------------
__global__ void prep_kernel(const float* __restrict__ wloc,
                            unsigned short* __restrict__ WTh,
                            int* __restrict__ flags)
{
    const int u = threadIdx.x;                 // 512 threads
    #pragma unroll
    for (int c = 0; c < F_; ++c)
        WTh[u * F_ + c] = f2bf(KKc * wloc[c * 512 + u]);
    __hip_atomic_store(&flags[u], 0, __ATOMIC_RELAXED, __HIP_MEMORY_SCOPE_AGENT);
}

// ---------------------------------------------------------------------------
// H1: flag-wait for step sn, then ISSUE next-step loads into registers.
// Values consumed one chain-section later (latency hidden under other chain).
// ---------------------------------------------------------------------------
__device__ __forceinline__ void h1_fn(int sn, int tid, int g, int w,
    int b, int ht, const float* __restrict__ dec,
    const float* kba, int u0,
    const float* __restrict__ prG, const float* __restrict__ paG,
    const float* __restrict__ PsG, int* __restrict__ myf,
    float& psv, float& hpa, float& hpr, float* qb)
{
    if (tid < NCH) {
        while (__hip_atomic_load(&myf[tid], __ATOMIC_RELAXED,
                                 __HIP_MEMORY_SCOPE_AGENT) < sn)
            __builtin_amdgcn_s_sleep(1);
    }
    __syncthreads();                       // order waves 1..15 behind the spin
    const int rp = (sn + 1) & 1;           // parity of step sn-1 data
    if (w < 2 && g < 16)
        psv = gldf(&PsG[rp * (B_ * NCH) + b * NCH + g]);
    if (w == 1 && ht >= 0) {
        size_t off = (size_t)rp * (B_ * TE) + (size_t)b * TE + ht;
        hpa = gldf(&paG[off]);
        hpr = gldf(&prG[off]);
    }
    const int sq = (sn < TD) ? sn : (TD - 1);
    const float* qrow = dec + ((size_t)b * TD + sq) * E_;
    qb[0] = fmaf(KKc, qrow[u0],      kba[0]);
    qb[1] = fmaf(KKc, qrow[u0 + 16], kba[1]);
}

// ---------------------------------------------------------------------------
// H2: full step compute for one chain (consumes H1's registers).
// phase1 -> bar -> conv -> bar -> MFMA+epilogue -> bar -> reduce+publish.
// ---------------------------------------------------------------------------
__device__ __forceinline__ void h2_fn(int s, int tid, int g, int w, int q, int n16,
    int b, int t0, int chunk, int ht, int hwi,
    const short8* bh, const float* vv, const __half2 (*er)[2][2],
    float psv, float hpa, float hpr, const float* qb,
    unsigned short* fThS, unsigned short* fTlS, const float* cwS,
    float* paW, float (*redT)[17], float* prS, float* paS,
    float* __restrict__ prG, float* __restrict__ paG, float* __restrict__ PsG,
    float* __restrict__ eout, int* __restrict__ myf, float cbR)
{
    const int wp = s & 1;
    const size_t rowB = (size_t)b * TE + t0;
    const float NKK = -KKc;

    if (s == 0) {
        if (tid < 98) paW[tid] = 0.0f;
        if (tid < CHUNK) {
            paS[tid] = 0.0f;
            gstf(&paG[wp * (B_ * TE) + rowB + tid], 0.0f);
        }
    } else if (w < 2) {
        float S = psv;
        S += __shfl_xor(S, 1); S += __shfl_xor(S, 2);
        S += __shfl_xor(S, 4); S += __shfl_xor(S, 8);
        S = __shfl(S, 0);
        const float inv = 1.0f / S;
        if (tid < CHUNK) {
            float pn  = prS[tid] * inv;
            float pan = paS[tid] + pn;
            paS[tid]      = pan;
            paW[KH + tid] = pan;
            eout[((size_t)b * TD + (s - 1)) * TE + t0 + tid] = pn;
            gstf(&paG[wp * (B_ * TE) + rowB + tid], pan);
        } else if (tid < CHUNK + 2 * KH) {
            paW[hwi] = (ht >= 0) ? fmaf(hpr, inv, hpa) : 0.0f;
        }
    }
    __syncthreads();

    // ---- conv -> fT bf16 hi/lo, A-operand layout [t][c]; 2 t/thread ----
    {
        const int c    = tid & 31;
        const int base = (tid >> 5) * 2;
        float a0 = cbR, a1 = cbR;
        #pragma unroll
        for (int k = 0; k < K_; ++k) {
            float wv = cwS[k * F_ + c];
            a0 = fmaf(wv, paW[base + k],     a0);
            a1 = fmaf(wv, paW[base + k + 1], a1);
        }
        unsigned short h0 = f2bf(a0), h1 = f2bf(a1);
        fThS[(base + 0) * F_ + c] = h0;
        fTlS[(base + 0) * F_ + c] = f2bf(a0 - bf2f(h0));
        fThS[(base + 1) * F_ + c] = h1;
        fTlS[(base + 1) * F_ + c] = f2bf(a1 - bf2f(h1));
    }
    __syncthreads();

    // ---- MFMA + fused epilogue ----
    const short8* AH = (const short8*)fThS;
    const short8* AL = (const short8*)fTlS;
    #pragma unroll
    for (int tt = 0; tt < 4; ++tt) {
        short8 ah = AH[(tt * 16 + n16) * 4 + q];
        short8 al = AL[(tt * 16 + n16) * 4 + q];
        float sacc[4] = {0.0f, 0.0f, 0.0f, 0.0f};
        #pragma unroll
        for (int ut = 0; ut < 2; ++ut) {
            float2 e01 = __half22float2(er[tt][ut][0]);
            float2 e23 = __half22float2(er[tt][ut][1]);
            f32x4 acc = (f32x4){qb[ut] + e01.x, qb[ut] + e01.y,
                                qb[ut] + e23.x, qb[ut] + e23.y};
            acc = __builtin_amdgcn_mfma_f32_16x16x32_bf16(ah, bh[ut], acc, 0, 0, 0);
            acc = __builtin_amdgcn_mfma_f32_16x16x32_bf16(al, bh[ut], acc, 0, 0, 0);
            #pragma unroll
            for (int r = 0; r < 4; ++r) {
                float rr = __builtin_amdgcn_exp2f(acc[r]);      // e^{2x}
                sacc[r] = fmaf(vv[ut],
                               __builtin_amdgcn_rcpf(rr + 1.0f), sacc[r]);
            }
        }
        #pragma unroll
        for (int r = 0; r < 4; ++r) {
            float sa = sacc[r];
            sa += __shfl_xor(sa, 1);
            sa += __shfl_xor(sa, 2);
            sa += __shfl_xor(sa, 4);
            sa += __shfl_xor(sa, 8);
            if (n16 == 0) redT[tt * 16 + q * 4 + r][w] = sa;
        }
    }
    __syncthreads();

    // ---- final: sum 16 wave-partials, p = exp2(-KK*red), publish ----
    if (tid < CHUNK) {
        float red = 0.0f;
        #pragma unroll
        for (int k = 0; k < 16; ++k) red += redT[tid][k];
        float p = __builtin_amdgcn_exp2f(red * NKK);
        prS[tid] = p;
        gstf(&prG[wp * (B_ * TE) + rowB + tid], p);
        float sp = p;
        #pragma unroll
        for (int off = 32; off; off >>= 1) sp += __shfl_xor(sp, off);
        if (tid == 0) {
            gstf(&PsG[wp * (B_ * NCH) + b * NCH + chunk], sp);
            asm volatile("s_waitcnt vmcnt(0)" ::: "memory");
            __hip_atomic_store(&myf[chunk], s + 1, __ATOMIC_RELAXED,
                               __HIP_MEMORY_SCOPE_AGENT);
        }
    }
    // no trailing barrier: the next section's H1 barrier orders all waves.
}

// ---------------------------------------------------------------------------
// Persistent kernel: 256 blocks x 1024 threads, 1 block/CU.
// Block (bA, chunk) interleaves two independent batch-chains (bA, bA+16):
// H2(A,s); H1(A,s+1); H2(B,s); H1(B,s+1) -- each chain's flag-wait + L3
// load latency is hidden under the other chain's compute, deterministically.
// ---------------------------------------------------------------------------
__global__ __launch_bounds__(1024, 4)
void persist_kernel(const float* __restrict__ enc,   // B,TE,E
                    const float* __restrict__ dec,   // B,TD,E
                    const float* __restrict__ cw,    // K,1,F
                    const float* __restrict__ cb,    // F
                    const unsigned short* __restrict__ WTh, // U,F bf16 (KK*W)
                    const float* __restrict__ va,    // U
                    const float* __restrict__ ba,    // U
                    float* __restrict__ prG,         // 2,B,TE
                    float* __restrict__ paG,         // 2,B,TE
                    float* __restrict__ PsG,         // 2,B,NCH
                    float* __restrict__ eout,        // B,TD,TE
                    int*   __restrict__ flags)       // B,NCH
{
    __shared__ __align__(16) unsigned short fThS[CHUNK * F_];
    __shared__ __align__(16) unsigned short fTlS[CHUNK * F_];
    __shared__ float cwS[K_ * F_];
    __shared__ float paW[98];
    __shared__ float redT[CHUNK][17];
    __shared__ float prSA[CHUNK], paSA[CHUNK];
    __shared__ float prSB[CHUNK], paSB[CHUNK];

    const int tid   = threadIdx.x;
    const int g     = tid & 63;
    const int w     = tid >> 6;               // wave 0..15
    const int q     = g >> 4;
    const int n16   = g & 15;
    const int bA    = blockIdx.x >> 4;        // 0..15
    const int bB    = bA + 16;                // 16..31
    const int chunk = blockIdx.x & 15;
    const int t0    = chunk * CHUNK;
    const int u0    = w * 32 + n16;

    // ---- per-session state (shared by both chains) ----
    short8 bh[2]; float vv[2], kba[2];
    #pragma unroll
    for (int ut = 0; ut < 2; ++ut) {
        const int u = u0 + ut * 16;
        bh[ut]  = ((const short8*)WTh)[u * 4 + q];
        vv[ut]  = va[u];
        kba[ut] = KKc * ba[u];
    }
    for (int i = tid; i < K_ * F_; i += 1024) cwS[i] = cw[i];
    const float cbR = cb[tid & 31];

    // halo geometry (fixed per lane; wave 1 lanes 0..29 own the halo)
    int ht = -1, hwi = 0;
    if (w == 1 && (tid - 64) < 2 * KH) {
        int hh = tid - 64;
        ht  = (hh < KH) ? (t0 - KH + hh) : (t0 + CHUNK + (hh - KH));
        hwi = (hh < KH) ? hh : (CHUNK + hh);
        if (ht < 0 || ht >= TE) ht = -1;
    }

    // ---- enc tiles -> registers (f16, KK-prescaled), one per chain ----
    __half2 erA[4][2][2], erB[4][2][2];
    #pragma unroll
    for (int tt = 0; tt < 4; ++tt)
        #pragma unroll
        for (int ut = 0; ut < 2; ++ut) {
            const int u = u0 + ut * 16;
            #pragma unroll
            for (int rp = 0; rp < 2; ++rp) {
                const int t = t0 + tt * 16 + q * 4 + rp * 2;
                float a0 = KKc * enc[((size_t)bA * TE + t) * E_ + u];
                float a1 = KKc * enc[((size_t)bA * TE + t + 1) * E_ + u];
                erA[tt][ut][rp] = __halves2half2(__float2half_rn(a0),
                                                 __float2half_rn(a1));
                float c0 = KKc * enc[((size_t)bB * TE + t) * E_ + u];
                float c1 = KKc * enc[((size_t)bB * TE + t + 1) * E_ + u];
                erB[tt][ut][rp] = __halves2half2(__float2half_rn(c0),
                                                 __float2half_rn(c1));
            }
        }

    int* myfA = flags + bA * NCH;
    int* myfB = flags + bB * NCH;

    // ---- prologue: qb for step 0 (no flag dependency) ----
    float qbA[2], qbB[2];
    {
        const float* qA = dec + ((size_t)bA * TD) * E_;
        const float* qB = dec + ((size_t)bB * TD) * E_;
        qbA[0] = fmaf(KKc, qA[u0],      kba[0]);
        qbA[1] = fmaf(KKc, qA[u0 + 16], kba[1]);
        qbB[0] = fmaf(KKc, qB[u0],      kba[0]);
        qbB[1] = fmaf(KKc, qB[u0 + 16], kba[1]);
    }
    float psvA = 0.f, hpaA = 0.f, hprA = 0.f;
    float psvB = 0.f, hpaB = 0.f, hprB = 0.f;
    __syncthreads();   // cwS ready before first conv

    for (int s = 0; s < TD; ++s) {
        h2_fn(s, tid, g, w, q, n16, bA, t0, chunk, ht, hwi,
              bh, vv, erA, psvA, hpaA, hprA, qbA,
              fThS, fTlS, cwS, paW, redT, prSA, paSA,
              prG, paG, PsG, eout, myfA, cbR);
        h1_fn(s + 1, tid, g, w, bA, ht, dec, kba, u0,
              prG, paG, PsG, myfA, psvA, hpaA, hprA, qbA);
        h2_fn(s, tid, g, w, q, n16, bB, t0, chunk, ht, hwi,
              bh, vv, erB, psvB, hpaB, hprB, qbB,
              fThS, fTlS, cwS, paW, redT, prSB, paSB,
              prG, paG, PsG, eout, myfB, cbR);
        h1_fn(s + 1, tid, g, w, bB, ht, dec, kba, u0,
              prG, paG, PsG, myfB, psvB, hpaB, hprB, qbB);
    }

    // ---- tail: normalize last step (psv from H1(.,TD)) into eout ----
    if (w == 0) {
        float S = psvA;
        S += __shfl_xor(S, 1); S += __shfl_xor(S, 2);
        S += __shfl_xor(S, 4); S += __shfl_xor(S, 8);
        S = __shfl(S, 0);
        float pn = prSA[g] * (1.0f / S);
        eout[((size_t)bA * TD + (TD - 1)) * TE + t0 + g] = pn;

        float Sb = psvB;
        Sb += __shfl_xor(Sb, 1); Sb += __shfl_xor(Sb, 2);
        Sb += __shfl_xor(Sb, 4); Sb += __shfl_xor(Sb, 8);
        Sb = __shfl(Sb, 0);
        float pnb = prSB[g] * (1.0f / Sb);
        eout[((size_t)bB * TD + (TD - 1)) * TE + t0 + g] = pnb;
    }
}

// ---------------------------------------------------------------------------
// Context matmul: c[b,d,e] = sum_t eo[b,d,t] * enc[b,t,e]
// ---------------------------------------------------------------------------
__global__ __launch_bounds__(256)
void context_kernel(const float* __restrict__ eo,   // B,TD,TE
                    const float* __restrict__ enc,  // B,TE,E
                    float* __restrict__ cout)       // B,TD,E
{
    __shared__ float eoT[64][36];
    const int b = blockIdx.y, d0 = blockIdx.x * 32, tid = threadIdx.x;

    float2 acc[32];
    #pragma unroll
    for (int d = 0; d < 32; ++d) { acc[d].x = 0.0f; acc[d].y = 0.0f; }

    for (int tc = 0; tc < TE / 64; ++tc) {
        __syncthreads();
        #pragma unroll
        for (int r = 0; r < 8; ++r) {
            int lin = r * 256 + tid;
            int d = lin >> 6, t = lin & 63;
            eoT[t][d] = eo[((size_t)b * TD + d0 + d) * TE + tc * 64 + t];
        }
        __syncthreads();
        #pragma unroll 4
        for (int t = 0; t < 64; ++t) {
            float2 ev = *(const float2*)&enc[((size_t)b * TE + tc * 64 + t) * E_ + 2 * tid];
            #pragma unroll
            for (int dq = 0; dq < 8; ++dq) {
                float4 wv = *(const float4*)&eoT[t][dq * 4];
                acc[dq * 4 + 0].x += wv.x * ev.x; acc[dq * 4 + 0].y += wv.x * ev.y;
                acc[dq * 4 + 1].x += wv.y * ev.x; acc[dq * 4 + 1].y += wv.y * ev.y;
                acc[dq * 4 + 2].x += wv.z * ev.x; acc[dq * 4 + 2].y += wv.z * ev.y;
                acc[dq * 4 + 3].x += wv.w * ev.x; acc[dq * 4 + 3].y += wv.w * ev.y;
            }
        }
    }
    #pragma unroll
    for (int d = 0; d < 32; ++d)
        *(float2*)&cout[((size_t)b * TD + d0 + d) * E_ + 2 * tid] = acc[d];
}

// ---------------------------------------------------------------------------
extern "C" void kernel_launch(void* const* d_in, const int* in_sizes, int n_in,
                              void* d_out, int out_size, void* d_ws, size_t ws_size,
                              hipStream_t stream) {
    const float* enc  = (const float*)d_in[0];
    const float* dec  = (const float*)d_in[1];
    const float* cw   = (const float*)d_in[2];
    const float* cb   = (const float*)d_in[3];
    const float* wloc = (const float*)d_in[4];
    const float* va   = (const float*)d_in[5];
    const float* ba   = (const float*)d_in[6];

    float* c_out = (float*)d_out;                          // B*TD*E
    float* e_out = (float*)d_out + (size_t)B_ * TD * E_;   // B*TD*TE

    float* ws  = (float*)d_ws;
    float* prG = ws;                                       // 2*B*TE
    float* paG = ws + 2 * (size_t)B_ * TE;                 // 2*B*TE
    float* PsG = ws + 4 * (size_t)B_ * TE;                 // 2*B*NCH
    unsigned short* WTh = (unsigned short*)(PsG + 2 * (size_t)B_ * NCH);
    int* flags = (int*)(WTh + 512 * F_);                   // B*NCH ints

    prep_kernel<<<1, 512, 0, stream>>>(wloc, WTh, flags);

    persist_kernel<<<NBLK, 1024, 0, stream>>>(
        enc, dec, cw, cb, WTh, va, ba,
        prG, paG, PsG, e_out, flags);

    context_kernel<<<dim3(TD / 32, B_), 256, 0, stream>>>(e_out, enc, c_out);
}